// Round 1
// baseline (356.126 us; speedup 1.0000x reference)
//
#include <hip/hip_runtime.h>

#define NB 512
#define NPG 256
#define NTOT (NB * NPG)
#define NEGMIN -3.4028234663852886e38f

// workspace layout (float offsets)
#define OFF_WNT 0       // WnT[64][16]
#define OFF_WCT 1024    // WcT[64][64]
#define OFF_W1AT 5120   // W1aT[128][64]  (rows 0..63 of W1, transposed)
#define OFF_W1BT 13312  // W1bT[128][64]  (rows 64..127 of W1, transposed)
#define OFF_BNC 21504   // bn + bc [64]
#define WS_FLOATS 21568

__global__ __launch_bounds__(256) void prep_kernel(
    const float* __restrict__ Wn, const float* __restrict__ bn,
    const float* __restrict__ Wc, const float* __restrict__ bc,
    const float* __restrict__ W1, float* __restrict__ ws)
{
    int i = blockIdx.x * 256 + threadIdx.x;
    if (i < 1024) {
        int d = i >> 4, k = i & 15;
        ws[OFF_WNT + i] = Wn[k * 64 + d];
    } else if (i < 5120) {
        int j = i - 1024; int d = j >> 6, k = j & 63;
        ws[OFF_WCT + j] = Wc[k * 64 + d];
    } else if (i < 13312) {
        int j = i - 5120; int r = j >> 6, k = j & 63;
        ws[OFF_W1AT + j] = W1[k * 128 + r];
    } else if (i < 21504) {
        int j = i - 13312; int r = j >> 6, k = j & 63;
        ws[OFF_W1BT + j] = W1[(64 + k) * 128 + r];
    } else if (i < WS_FLOATS) {
        int d = i - OFF_BNC;
        ws[OFF_BNC + d] = bn[d] + bc[d];
    }
}

// One block per graph. Thread t owns node t (local). h[64] in VGPRs,
// h tile staged in LDS (XOR-swizzled 16B chunks) for the 16-neighbor gather.
__global__ __launch_bounds__(256, 2) void gdqn_kernel(
    const float* __restrict__ nfg, const int* __restrict__ esrcg,
    const int* __restrict__ fmask, const float* __restrict__ ws,
    const float* __restrict__ bn, const float* __restrict__ b1,
    const float* __restrict__ W2, const float* __restrict__ b2,
    float* __restrict__ out)
{
    extern __shared__ float smem[];
    float* hsh  = smem;                     // 256*64 = 16384 (swizzled rows)
    float* part = smem + 16384;             // 256
    float* gesh = smem + 16640;             // 64
    float* rpsh = smem + 16704;             // 128
    float* redv = smem + 16832;             // 4
    int*   redi = (int*)(smem + 16836);     // 4

    const int g = blockIdx.x, t = threadIdx.x;
    const int node = (g << 8) + t;

    const float* WnT  = ws + OFF_WNT;
    const float* WcT  = ws + OFF_WCT;
    const float* W1aT = ws + OFF_W1AT;
    const float* W1bT = ws + OFF_W1BT;
    const float* bnc  = ws + OFF_BNC;

    // node features (16 floats) -> regs
    float nf[16];
    {
        const float4* p = (const float4*)(nfg + node * 16);
        float4 a = p[0], b = p[1], c = p[2], d = p[3];
        nf[0]=a.x; nf[1]=a.y; nf[2]=a.z; nf[3]=a.w;
        nf[4]=b.x; nf[5]=b.y; nf[6]=b.z; nf[7]=b.w;
        nf[8]=c.x; nf[9]=c.y; nf[10]=c.z; nf[11]=c.w;
        nf[12]=d.x; nf[13]=d.y; nf[14]=d.z; nf[15]=d.w;
    }
    // 16 in-edges of this node; local index = src & 255 (intra-graph edges)
    int es[16];
    {
        const int4* p = (const int4*)(esrcg + node * 16);
        int4 a = p[0], b = p[1], c = p[2], d = p[3];
        es[0]=a.x&255; es[1]=a.y&255; es[2]=a.z&255; es[3]=a.w&255;
        es[4]=b.x&255; es[5]=b.y&255; es[6]=b.z&255; es[7]=b.w&255;
        es[8]=c.x&255; es[9]=c.y&255; es[10]=c.z&255; es[11]=c.w&255;
        es[12]=d.x&255; es[13]=d.y&255; es[14]=d.z&255; es[15]=d.w&255;
    }

    // h = relu(nf @ Wn + bn)   (WnT scalar-loaded: wave-uniform)
    float h[64];
    #pragma unroll 8
    for (int d = 0; d < 64; ++d) {
        float s = bn[d];
        #pragma unroll
        for (int k = 0; k < 16; ++k) s = fmaf(nf[k], WnT[d * 16 + k], s);
        h[d] = fmaxf(s, 0.0f);
    }

    const int swt = t & 7;
    {
        float4* dst = (float4*)(hsh + (t << 6));
        #pragma unroll
        for (int c = 0; c < 16; ++c)
            dst[c ^ swt] = make_float4(h[4*c], h[4*c+1], h[4*c+2], h[4*c+3]);
    }
    __syncthreads();

    for (int lv = 0; lv < 3; ++lv) {
        // gather-sum 16 neighbor rows from LDS
        float pooled[64];
        #pragma unroll
        for (int k = 0; k < 64; ++k) pooled[k] = 0.0f;
        #pragma unroll
        for (int j = 0; j < 16; ++j) {
            int s = es[j];
            const float4* row = (const float4*)(hsh + (s << 6));
            int sw = s & 7;
            #pragma unroll
            for (int c = 0; c < 16; ++c) {
                float4 v = row[c ^ sw];
                pooled[4*c+0] += v.x; pooled[4*c+1] += v.y;
                pooled[4*c+2] += v.z; pooled[4*c+3] += v.w;
            }
        }
        __syncthreads();  // all reads of old h done

        // h = relu(pooled @ Wc + (bn+bc) + nf@Wn)  (input_msg recomputed)
        #pragma unroll 4
        for (int d = 0; d < 64; ++d) {
            float s = bnc[d];
            #pragma unroll
            for (int k = 0; k < 16; ++k) s = fmaf(nf[k], WnT[d * 16 + k], s);
            const float* wr = WcT + d * 64;
            #pragma unroll
            for (int k = 0; k < 64; ++k) s = fmaf(pooled[k], wr[k], s);
            h[d] = fmaxf(s, 0.0f);
        }
        {
            float4* dst = (float4*)(hsh + (t << 6));
            #pragma unroll
            for (int c = 0; c < 16; ++c)
                dst[c ^ swt] = make_float4(h[4*c], h[4*c+1], h[4*c+2], h[4*c+3]);
        }
        __syncthreads();
    }

    // graph_embed = relu(sum over nodes of h)
    {
        int col = t & 63, v0 = (t >> 6) << 6;
        float s = 0.0f;
        #pragma unroll 8
        for (int v = 0; v < 64; ++v) {
            int vv = v0 + v;
            s += hsh[(vv << 6) + ((((col >> 2) ^ (vv & 7)) << 2) | (col & 3))];
        }
        part[t] = s;
    }
    __syncthreads();
    if (t < 64) {
        float s = part[t] + part[t + 64] + part[t + 128] + part[t + 192];
        gesh[t] = fmaxf(s, 0.0f);
    }
    __syncthreads();
    // rep_proj[j] = b1[j] + sum_k ge[k] * W1[64+k][j]   (block-uniform half of MLP)
    if (t < 128) {
        float s = b1[t];
        const float4* wr = (const float4*)(W1bT + t * 64);
        #pragma unroll
        for (int c = 0; c < 16; ++c) {
            float4 w = wr[c];
            s = fmaf(gesh[4*c+0], w.x, s);
            s = fmaf(gesh[4*c+1], w.y, s);
            s = fmaf(gesh[4*c+2], w.z, s);
            s = fmaf(gesh[4*c+3], w.w, s);
        }
        rpsh[t] = s;
    }
    __syncthreads();

    // raw_pred = relu([h, rep] @ W1 + b1) @ W2 + b2  (per-thread half only)
    float raw = b2[0];
    #pragma unroll 2
    for (int j = 0; j < 128; ++j) {
        float z = rpsh[j];
        const float* wr = W1aT + j * 64;
        #pragma unroll
        for (int k = 0; k < 64; ++k) z = fmaf(h[k], wr[k], z);
        raw = fmaf(fmaxf(z, 0.0f), W2[j], raw);
    }
    out[512 + node] = raw;

    // masked max/argmax over the graph (first-index tie-break like jnp.argmax)
    float q = fmask[node] ? NEGMIN : raw;
    int idx = t;
    #pragma unroll
    for (int off = 32; off >= 1; off >>= 1) {
        float ov = __shfl_down(q, off, 64);
        int oi  = __shfl_down(idx, off, 64);
        if (ov > q || (ov == q && oi < idx)) { q = ov; idx = oi; }
    }
    if ((t & 63) == 0) { redv[t >> 6] = q; redi[t >> 6] = idx; }
    __syncthreads();
    if (t == 0) {
        float bv = redv[0]; int bi = redi[0];
        #pragma unroll
        for (int w = 1; w < 4; ++w) {
            float v = redv[w]; int iw = redi[w];
            if (v > bv || (v == bv && iw < bi)) { bv = v; bi = iw; }
        }
        out[g] = (float)bi;             // indices (as float)
        out[512 + NTOT + g] = bv;       // values
    }
}

extern "C" void kernel_launch(void* const* d_in, const int* in_sizes, int n_in,
                              void* d_out, int out_size, void* d_ws, size_t ws_size,
                              hipStream_t stream)
{
    const float* nfg   = (const float*)d_in[0];
    const int*   esrc  = (const int*)d_in[1];
    // d_in[2] edge_dst, d_in[3] seg_ids: implicit in the fixed layout
    const int*   fmask = (const int*)d_in[4];
    const float* Wn = (const float*)d_in[5];
    const float* bn = (const float*)d_in[6];
    const float* Wc = (const float*)d_in[7];
    const float* bc = (const float*)d_in[8];
    const float* W1 = (const float*)d_in[9];
    const float* b1 = (const float*)d_in[10];
    const float* W2 = (const float*)d_in[11];
    const float* b2 = (const float*)d_in[12];
    float* out = (float*)d_out;
    float* ws  = (float*)d_ws;

    prep_kernel<<<(WS_FLOATS + 255) / 256, 256, 0, stream>>>(Wn, bn, Wc, bc, W1, ws);

    size_t shmem = 16840 * sizeof(float);  // 67,360 B > 64 KB default -> opt in
    hipFuncSetAttribute((const void*)gdqn_kernel,
                        hipFuncAttributeMaxDynamicSharedMemorySize, (int)shmem);
    gdqn_kernel<<<NB, 256, shmem, stream>>>(nfg, esrc, fmask, ws, bn, b1, W2, b2, out);
}

// Round 2
// 260.049 us; speedup vs baseline: 1.3695x; 1.3695x over previous
//
#include <hip/hip_runtime.h>

#define NB 512
#define NPG 256
#define NTOT (NB * NPG)
#define NEGMIN -3.4028234663852886e38f

// workspace layout (float offsets)
#define OFF_WNT 0       // WnT[64][16]   WnT[d][k] = Wn[k][d]
#define OFF_WCT 1024    // WcT[64][64]   WcT[d][k] = Wc[k][d]
#define OFF_W1AT 5120   // W1aT[128][64] W1aT[j][k] = W1[k][j]      (rows 0..63 of W1)
#define OFF_W1BT 13312  // W1bT[128][64] W1bT[j][k] = W1[64+k][j]   (rows 64..127)
#define OFF_BNC 21504   // bn + bc [64]
#define WS_FLOATS 21568

__global__ __launch_bounds__(256) void prep_kernel(
    const float* __restrict__ Wn, const float* __restrict__ bn,
    const float* __restrict__ Wc, const float* __restrict__ bc,
    const float* __restrict__ W1, float* __restrict__ ws)
{
    int i = blockIdx.x * 256 + threadIdx.x;
    if (i < 1024) {
        int d = i >> 4, k = i & 15;
        ws[OFF_WNT + i] = Wn[k * 64 + d];
    } else if (i < 5120) {
        int j = i - 1024; int d = j >> 6, k = j & 63;
        ws[OFF_WCT + j] = Wc[k * 64 + d];
    } else if (i < 13312) {
        int j = i - 5120; int r = j >> 6, k = j & 63;
        ws[OFF_W1AT + j] = W1[k * 128 + r];
    } else if (i < 21504) {
        int j = i - 13312; int r = j >> 6, k = j & 63;
        ws[OFF_W1BT + j] = W1[(64 + k) * 128 + r];
    } else if (i < WS_FLOATS) {
        int d = i - OFF_BNC;
        ws[OFF_BNC + d] = bn[d] + bc[d];
    }
}

// One block per graph. Thread t owns node t. h lives ONLY in LDS during the
// message-passing levels (register arrays are never dynamically indexed ->
// no scratch spill). XOR-swizzled 16B chunks: row r chunk c at slot c^(r&7).
__global__ __launch_bounds__(256, 2) void gdqn_kernel(
    const float* __restrict__ nfg, const int* __restrict__ esrcg,
    const int* __restrict__ fmask, const float* __restrict__ ws,
    const float* __restrict__ bn, const float* __restrict__ b1,
    const float* __restrict__ W2, const float* __restrict__ b2,
    float* __restrict__ out)
{
    extern __shared__ float smem[];
    float* hsh  = smem;                     // 256*64 = 16384 (swizzled rows)
    float* part = smem + 16384;             // 256
    float* gesh = smem + 16640;             // 64
    float* rpsh = smem + 16704;             // 128
    float* redv = smem + 16832;             // 4
    int*   redi = (int*)(smem + 16836);     // 4

    const int g = blockIdx.x, t = threadIdx.x;
    const int node = (g << 8) + t;
    const int swt = t & 7;
    float* myrow = hsh + (t << 6);

    const float* WnT  = ws + OFF_WNT;
    const float* WcT  = ws + OFF_WCT;
    const float* W1aT = ws + OFF_W1AT;
    const float* bnc  = ws + OFF_BNC;

    // node features (16 floats) -> regs (always statically indexed)
    float nf[16];
    {
        const float4* p = (const float4*)(nfg + node * 16);
        float4 a = p[0], b = p[1], c = p[2], d = p[3];
        nf[0]=a.x; nf[1]=a.y; nf[2]=a.z; nf[3]=a.w;
        nf[4]=b.x; nf[5]=b.y; nf[6]=b.z; nf[7]=b.w;
        nf[8]=c.x; nf[9]=c.y; nf[10]=c.z; nf[11]=c.w;
        nf[12]=d.x; nf[13]=d.y; nf[14]=d.z; nf[15]=d.w;
    }
    int es[16];
    {
        const int4* p = (const int4*)(esrcg + node * 16);
        int4 a = p[0], b = p[1], c = p[2], d = p[3];
        es[0]=a.x&255; es[1]=a.y&255; es[2]=a.z&255; es[3]=a.w&255;
        es[4]=b.x&255; es[5]=b.y&255; es[6]=b.z&255; es[7]=b.w&255;
        es[8]=c.x&255; es[9]=c.y&255; es[10]=c.z&255; es[11]=c.w&255;
        es[12]=d.x&255; es[13]=d.y&255; es[14]=d.z&255; es[15]=d.w&255;
    }

    // h0 = relu(nf @ Wn + bn) -> straight to LDS (never a reg array)
    for (int c = 0; c < 16; ++c) {          // c is wave-uniform
        float s4[4];
        #pragma unroll
        for (int q = 0; q < 4; ++q) {       // fully unrolled: static indices
            int d = 4 * c + q;
            float s = bn[d];
            #pragma unroll
            for (int k = 0; k < 16; ++k) s = fmaf(nf[k], WnT[d * 16 + k], s);
            s4[q] = fmaxf(s, 0.0f);
        }
        ((float4*)myrow)[c ^ swt] = make_float4(s4[0], s4[1], s4[2], s4[3]);
    }
    __syncthreads();

    for (int lv = 0; lv < 3; ++lv) {
        // gather-sum 16 neighbor rows from LDS into regs (static indices only)
        float pooled[64];
        #pragma unroll
        for (int k = 0; k < 64; ++k) pooled[k] = 0.0f;
        #pragma unroll
        for (int j = 0; j < 16; ++j) {
            int s = es[j];
            const float4* row = (const float4*)(hsh + (s << 6));
            int sw = s & 7;
            #pragma unroll
            for (int c = 0; c < 16; ++c) {
                float4 v = row[c ^ sw];
                pooled[4*c+0] += v.x; pooled[4*c+1] += v.y;
                pooled[4*c+2] += v.z; pooled[4*c+3] += v.w;
            }
        }
        __syncthreads();  // all reads of old h done before overwrite

        // h = relu(pooled @ Wc + (bn+bc) + nf@Wn), written directly to LDS
        for (int c = 0; c < 16; ++c) {      // c wave-uniform
            float s4[4];
            #pragma unroll
            for (int q = 0; q < 4; ++q) {
                int d = 4 * c + q;
                float s = bnc[d];
                #pragma unroll
                for (int k = 0; k < 16; ++k) s = fmaf(nf[k], WnT[d * 16 + k], s);
                const float* wr = WcT + d * 64;
                #pragma unroll
                for (int k = 0; k < 64; ++k) s = fmaf(pooled[k], wr[k], s);
                s4[q] = fmaxf(s, 0.0f);
            }
            ((float4*)myrow)[c ^ swt] = make_float4(s4[0], s4[1], s4[2], s4[3]);
        }
        __syncthreads();
    }

    // graph_embed = relu(sum over nodes of h)
    {
        int col = t & 63, v0 = (t >> 6) << 6;
        float s = 0.0f;
        for (int v = 0; v < 64; ++v) {
            int vv = v0 + v;
            s += hsh[(vv << 6) + ((((col >> 2) ^ (vv & 7)) << 2) | (col & 3))];
        }
        part[t] = s;
    }
    __syncthreads();
    if (t < 64) {
        float s = part[t] + part[t + 64] + part[t + 128] + part[t + 192];
        gesh[t] = fmaxf(s, 0.0f);
    }
    __syncthreads();
    // rep_proj[j] = b1[j] + sum_k ge[k] * W1[64+k][j]  (block-uniform MLP half)
    if (t < 128) {
        float s = b1[t];
        const float4* wr = (const float4*)(ws + OFF_W1BT + t * 64);
        #pragma unroll
        for (int c = 0; c < 16; ++c) {
            float4 w = wr[c];
            s = fmaf(gesh[4*c+0], w.x, s);
            s = fmaf(gesh[4*c+1], w.y, s);
            s = fmaf(gesh[4*c+2], w.z, s);
            s = fmaf(gesh[4*c+3], w.w, s);
        }
        rpsh[t] = s;
    }

    // reload this node's h from LDS into regs (static chunk unroll; pooled/es
    // are dead here so the live set is small)
    float h[64];
    #pragma unroll
    for (int c = 0; c < 16; ++c) {
        float4 v = ((const float4*)myrow)[c ^ swt];
        h[4*c+0] = v.x; h[4*c+1] = v.y; h[4*c+2] = v.z; h[4*c+3] = v.w;
    }
    __syncthreads();

    // raw_pred = relu([h, rep] @ W1 + b1) @ W2 + b2  (per-node half only)
    float raw = b2[0];
    for (int j = 0; j < 128; ++j) {         // j wave-uniform; h[k] static
        float z = rpsh[j];
        const float* wr = W1aT + j * 64;
        #pragma unroll
        for (int k = 0; k < 64; ++k) z = fmaf(h[k], wr[k], z);
        raw = fmaf(fmaxf(z, 0.0f), W2[j], raw);
    }
    out[512 + node] = raw;

    // masked max/argmax over the graph (first-index tie-break like jnp.argmax)
    float q = fmask[node] ? NEGMIN : raw;
    int idx = t;
    #pragma unroll
    for (int off = 32; off >= 1; off >>= 1) {
        float ov = __shfl_down(q, off, 64);
        int oi  = __shfl_down(idx, off, 64);
        if (ov > q || (ov == q && oi < idx)) { q = ov; idx = oi; }
    }
    if ((t & 63) == 0) { redv[t >> 6] = q; redi[t >> 6] = idx; }
    __syncthreads();
    if (t == 0) {
        float bv = redv[0]; int bi = redi[0];
        #pragma unroll
        for (int w = 1; w < 4; ++w) {
            float v = redv[w]; int iw = redi[w];
            if (v > bv || (v == bv && iw < bi)) { bv = v; bi = iw; }
        }
        out[g] = (float)bi;             // indices (as float)
        out[512 + NTOT + g] = bv;       // values
    }
}

extern "C" void kernel_launch(void* const* d_in, const int* in_sizes, int n_in,
                              void* d_out, int out_size, void* d_ws, size_t ws_size,
                              hipStream_t stream)
{
    const float* nfg   = (const float*)d_in[0];
    const int*   esrc  = (const int*)d_in[1];
    const int*   fmask = (const int*)d_in[4];
    const float* Wn = (const float*)d_in[5];
    const float* bn = (const float*)d_in[6];
    const float* Wc = (const float*)d_in[7];
    const float* bc = (const float*)d_in[8];
    const float* W1 = (const float*)d_in[9];
    const float* b1 = (const float*)d_in[10];
    const float* W2 = (const float*)d_in[11];
    const float* b2 = (const float*)d_in[12];
    float* out = (float*)d_out;
    float* ws  = (float*)d_ws;

    prep_kernel<<<(WS_FLOATS + 255) / 256, 256, 0, stream>>>(Wn, bn, Wc, bc, W1, ws);

    size_t shmem = 16840 * sizeof(float);  // 67,360 B > 64 KB default -> opt in
    hipFuncSetAttribute((const void*)gdqn_kernel,
                        hipFuncAttributeMaxDynamicSharedMemorySize, (int)shmem);
    gdqn_kernel<<<NB, 256, shmem, stream>>>(nfg, esrc, fmask, ws, bn, b1, W2, b2, out);
}